// Round 12
// baseline (249.725 us; speedup 1.0000x reference)
//
#include <hip/hip_runtime.h>
#include <hip/hip_bf16.h>
#include <stdint.h>

typedef __attribute__((ext_vector_type(8))) short bf16x8;
typedef __attribute__((ext_vector_type(4))) float f32x4;
typedef __attribute__((ext_vector_type(16))) float f32x16;

__device__ __forceinline__ unsigned short f2bf(float x) {
    union { float f; unsigned u; } u; u.f = x;
    unsigned r = u.u + 0x7FFFu + ((u.u >> 16) & 1u);
    return (unsigned short)(r >> 16);
}

// native packed f32->bf16 (gfx950 has no builtin; header fn is software RNE)
__device__ __forceinline__ unsigned pkbf(float a, float b) {
    unsigned r;
    asm("v_cvt_pk_bf16_f32 %0, %1, %2" : "=v"(r) : "v"(a), "v"(b));
    return r;
}

__device__ __forceinline__ float exp2a(float x) {
    float r; asm("v_exp_f32 %0, %1" : "=v"(r) : "v"(x)); return r;
}

__device__ __forceinline__ void gload_lds16(const void* g, void* s) {
    __builtin_amdgcn_global_load_lds(
        (const __attribute__((address_space(1))) void*)g,
        (__attribute__((address_space(3))) void*)s,
        16, 0, 0);
}

#define LOG2E 1.44269504088896f

// ---------------- fp32 -> bf16 convert ----------------
__global__ void cvt_kernel(const float* __restrict__ in,
                           unsigned* __restrict__ out, int n4) {
    int i = blockIdx.x * blockDim.x + threadIdx.x;
    if (i >= n4) return;
    float4 v = ((const float4*)in)[i];
    uint2 o;
    o.x = pkbf(v.x, v.y);
    o.y = pkbf(v.z, v.w);
    ((uint2*)out)[i] = o;
}

// all four 1024x1024 weights in one launch (each = 2^18 float4 groups)
__global__ void cvt4_kernel(const float* __restrict__ w0, const float* __restrict__ w1,
                            const float* __restrict__ w2, const float* __restrict__ w3,
                            unsigned* __restrict__ o0, unsigned* __restrict__ o1,
                            unsigned* __restrict__ o2, unsigned* __restrict__ o3) {
    int i = blockIdx.x * blockDim.x + threadIdx.x;
    int w = i >> 18, j = i & 262143;
    const float* src = (w == 0) ? w0 : (w == 1) ? w1 : (w == 2) ? w2 : w3;
    unsigned* dst = (w == 0) ? o0 : (w == 1) ? o1 : (w == 2) ? o2 : o3;
    float4 v = ((const float4*)src)[j];
    uint2 o;
    o.x = pkbf(v.x, v.y);
    o.y = pkbf(v.z, v.w);
    ((uint2*)dst)[j] = o;
}

// ---------------- mask ballot words: mw[b*32+t] = ballot(mask[b][t*64+lane]==0)
__global__ void maskw_kernel(const int* __restrict__ mask,
                             unsigned long long* __restrict__ mw) {
    int gw = blockIdx.x * 4 + (threadIdx.x >> 6);
    int lane = threadIdx.x & 63;
    int b = gw >> 5, t = gw & 31;
    unsigned long long z = __ballot(mask[b * 2048 + t * 64 + lane] == 0);
    if (lane == 0) mw[gw] = z;
}

// ---------------- 256x128-tile GEMM, 4-phase counted-vmcnt schedule --------
// C = A[M][1024] * B[N][1024]^T, bf16 in, fp32 acc. BK=64, 8 waves (4M x 2N),
// per-wave 64x64 (acc[4][4] f32x4). LDS: 3-slot ring x (A 32KB + B 16KB) =
// 144KB, 1 block/CU. Chunked conflict-free layout [chunk c][row] in 16B units
// (r8-proven: 0 bank conflicts). Per K-tile: 4 phases, each {ds_read A-frag
// (mf=q) + stage 2 loads of tile t+2 -> barrier -> 8 MFMA (setprio) ->
// barrier}; vmcnt(6) once per K-tile (t+2's 6 loads in flight, never 0 in
// steady state). Ring mod 3: stage target (t+2)%3 != read slot t%3; cross-
// iter safety via phase-3 vmcnt + barrier.
// MODE 0: qkv (sel = by>>5: 0 Q scaled log2e/8, 1 K, 2 V^T k-permuted)
// MODE 1: out projection, fp32 row-major + bias
template<int MODE>
__global__ __launch_bounds__(512, 2)
void gemm256(const short* __restrict__ A,
             const short* __restrict__ B0, const short* __restrict__ B1,
             const short* __restrict__ B2,
             const float* __restrict__ bi0, const float* __restrict__ bi1,
             const float* __restrict__ bi2,
             void* __restrict__ O0, void* __restrict__ O1, void* __restrict__ O2)
{
    __shared__ __align__(16) char lds[3 * 49152];   // slot: A 32KB + B 16KB

    const int tid  = threadIdx.x;
    const int lane = tid & 63;
    const int wave = tid >> 6;

    int sel, bm, bn;
    if (MODE == 0) {
        sel = blockIdx.y >> 5;
        bm  = (blockIdx.y & 31) * 256;
        bn  = blockIdx.x * 128;
    } else {
        sel = 0;
        bm  = blockIdx.y * 256;
        bn  = blockIdx.x * 128;
    }
    const short* Bg = (sel == 0) ? B0 : (sel == 1) ? B1 : B2;
    const float* bias = (sel == 0) ? bi0 : (sel == 1) ? bi1 : bi2;

    const int wm = (wave >> 1) * 64;    // 4 M-waves
    const int wn = (wave & 1) * 64;     // 2 N-waves

    // per-lane LDS frag bases (bytes within a slot)
    const int aoff = (((lane >> 4) << 8) + wm + (lane & 15)) << 4;           // A: chunk row 256
    const int boff = (((lane >> 4) << 7) + wn + (lane & 15)) << 4;           // B: chunk row 128

    f32x4 acc[4][4] = {};
    bf16x8 bfr[4][2];

    // stage helpers: linear LDS dest (wave-uniform base + lane*16), per-lane src
    auto stageA = [&](int slot, int k0, int p) {
        gload_lds16(A + (size_t)(bm + (tid & 255)) * 1024 + k0 + (p * 2 + (tid >> 8)) * 8,
                    lds + slot * 49152 + (p * 512 + wave * 64) * 16);
    };
    auto stageB = [&](int slot, int k0, int p) {
        gload_lds16(Bg + (size_t)(bn + (tid & 127)) * 1024 + k0 + (p * 4 + (tid >> 7)) * 8,
                    lds + slot * 49152 + 32768 + (p * 512 + wave * 64) * 16);
    };
    auto stageTile = [&](int slot, int k0) {
#pragma unroll
        for (int p = 0; p < 4; ++p) stageA(slot, k0, p);
#pragma unroll
        for (int p = 0; p < 2; ++p) stageB(slot, k0, p);
    };

    // prologue: tiles 0,1 staged; wait tile 0 (its 6 loads are the oldest)
    stageTile(0, 0);
    stageTile(1, 64);
    asm volatile("s_waitcnt vmcnt(6)" ::: "memory");
    __builtin_amdgcn_s_barrier();

    for (int t = 0; t < 16; ++t) {
        const char* As = lds + (t % 3) * 49152;
        const char* Bs = As + 32768;
        const int s2 = (t + 2) % 3;
        const int k2 = (t + 2) * 64;
        const bool pre = (t + 2 < 16);

#pragma unroll
        for (int q = 0; q < 4; ++q) {
            if (q == 0) {
#pragma unroll
                for (int nf = 0; nf < 4; ++nf) {
                    bfr[nf][0] = *(const bf16x8*)(Bs + boff + nf * 256);
                    bfr[nf][1] = *(const bf16x8*)(Bs + boff + 8192 + nf * 256);
                }
            }
            bf16x8 a0 = *(const bf16x8*)(As + aoff + q * 256);
            bf16x8 a1 = *(const bf16x8*)(As + aoff + 16384 + q * 256);

            if (pre) {
                if (q == 0) { stageA(s2, k2, 0); stageA(s2, k2, 1); }
                else if (q == 1) { stageA(s2, k2, 2); stageA(s2, k2, 3); }
                else if (q == 2) { stageB(s2, k2, 0); stageB(s2, k2, 1); }
            }
            if (q == 3) {
                if (t < 14) asm volatile("s_waitcnt vmcnt(6)" ::: "memory");
                else        asm volatile("s_waitcnt vmcnt(0)" ::: "memory");
            }
            __builtin_amdgcn_s_barrier();
            __builtin_amdgcn_s_setprio(1);
#pragma unroll
            for (int nf = 0; nf < 4; ++nf)
                acc[q][nf] = __builtin_amdgcn_mfma_f32_16x16x32_bf16(
                    a0, bfr[nf][0], acc[q][nf], 0, 0, 0);
#pragma unroll
            for (int nf = 0; nf < 4; ++nf)
                acc[q][nf] = __builtin_amdgcn_mfma_f32_16x16x32_bf16(
                    a1, bfr[nf][1], acc[q][nf], 0, 0, 0);
            __builtin_amdgcn_s_setprio(0);
            __builtin_amdgcn_s_barrier();
        }
    }

    // ---- epilogue (index math identical to proven 128^2 kernel) ----
    const int ccol  = lane & 15;
    const int crow0 = (lane >> 4) * 4;
#pragma unroll
    for (int nf = 0; nf < 4; ++nf) {
        int gn = bn + wn + nf * 16 + ccol;
        float bv2 = bias[gn];
        int h = gn >> 6, d = gn & 63;
#pragma unroll
        for (int mf = 0; mf < 4; ++mf) {
            int gm0 = bm + wm + mf * 16 + crow0;
            if (MODE == 1) {
                float* out = (float*)O0;
#pragma unroll
                for (int r = 0; r < 4; ++r)
                    out[(size_t)(gm0 + r) * 1024 + gn] = acc[mf][nf][r] + bv2;
            } else {
                int b = gm0 >> 11, q = gm0 & 2047;
                if (sel == 2) {
                    // V^T with k-position perm: swap middle 4-groups per 16-block
                    int g4 = (q >> 2) & 3;
                    int qp = q ^ (((g4 + 1) & 2) ? 12 : 0);
                    size_t base = ((size_t)(b * 16 + h) * 64 + d) * 2048 + qp;
                    uint2 w2;
                    w2.x = pkbf(acc[mf][nf][0] + bv2, acc[mf][nf][1] + bv2);
                    w2.y = pkbf(acc[mf][nf][2] + bv2, acc[mf][nf][3] + bv2);
                    *(uint2*)((unsigned short*)O2 + base) = w2;
                } else {
                    unsigned short* out = (sel == 0) ? (unsigned short*)O0
                                                     : (unsigned short*)O1;
                    float scale = (sel == 0) ? (0.125f * LOG2E) : 1.0f;
                    size_t base = ((size_t)(b * 16 + h) * 2048 + q) * 64 + d;
#pragma unroll
                    for (int r = 0; r < 4; ++r)
                        out[base + (size_t)r * 64] =
                            f2bf((acc[mf][nf][r] + bv2) * scale);
                }
            }
        }
    }
}

// ---------------- flash attention (32x32 mfma, 3-slot ring, counted vmcnt) -
// Q,K: bf16 [64][2048][64] (Q pre-scaled by log2e/8); VT: bf16 [64][64][2048]
// (k-permuted). mw: mask ballot words. ctx out bf16 [4][2048][1024]
// m=2 (64 q-rows/wave), grid (8,64). Chunked conflict-free LDS (r8).
__global__ __launch_bounds__(256, 2)
void attn_kernel(const short* __restrict__ Q, const short* __restrict__ Kg,
                 const short* __restrict__ VTg,
                 const unsigned long long* __restrict__ mw,
                 unsigned short* __restrict__ ctx)
{
    __shared__ __align__(16) short Ks[3][4096];   // 8KB/slot: [c][row] 16B units
    __shared__ __align__(16) short Vt[3][4096];   // 8KB/slot: [c][d-row]
    __shared__ unsigned long long mz[32];

    const int tid  = threadIdx.x;
    const int lane = tid & 63;
    const int wave = tid >> 6;
    const int l31  = lane & 31;
    const int hi   = lane >> 5;

    // XCD swizzle: 8 q-tiles of a (b,h) share one XCD's L2
    const int lin = blockIdx.y * 8 + blockIdx.x;   // gridDim = (8, 64)
    const int bh  = (lin & 7) * 8 + ((lin >> 3) & 7);
    const int qt  = lin >> 6;
    const int bb = bh >> 4, hh = bh & 15;

    const size_t hbase = (size_t)bh * (2048 * 64);
    const short* Qb  = Q   + hbase;
    const short* Kb  = Kg  + hbase;
    const short* VTb = VTg + hbase;      // [64][2048]
    const unsigned long long* mwb = mw + bb * 32;

    const int q0 = qt * 256 + wave * 64;

    // every wave writes all 32 mask words (identical values; self-visible)
    if (lane < 32) mz[lane] = mwb[lane];

    // Q fragments (B-operand): col=q=lane&31, k^=hi*8+e
    bf16x8 qf[2][4];
#pragma unroll
    for (int m = 0; m < 2; ++m)
#pragma unroll
        for (int s = 0; s < 4; ++s) {
            int row = q0 + m * 32 + l31;
            qf[m][s] = *(const bf16x8*)(Qb + (size_t)row * 64 + s * 16 + hi * 8);
        }

    // per-lane LDS byte base
    const int rb = hi * 1024 + l31 * 16;

    f32x16 o[2][2] = {};            // [m][nd]
    float li[2] = { 0.f, 0.f };

    // stage tile kt0/64 into ring slot: LDS[c][row], c=p*4+wave, row=lane
    auto stage = [&](int slot, int kt0) {
#pragma unroll
        for (int p = 0; p < 2; ++p) {
            gload_lds16(Kb + (size_t)(kt0 + lane) * 64 + (p * 4 + wave) * 8,
                        (char*)&Ks[slot][0] + p * 4096 + wave * 1024);
            gload_lds16(VTb + (size_t)lane * 2048 + kt0 + (p * 4 + wave) * 8,
                        (char*)&Vt[slot][0] + p * 4096 + wave * 1024);
        }
    };

    auto body = [&](int slot, int t) {
        const char* ks = (const char*)&Ks[slot][0];
        const char* vt = (const char*)&Vt[slot][0];

        // ---- QK^T (swapped): S^T[k][q]; A-frag row=kt*32+l31, chunk=2s+hi ----
        f32x16 sA[2][2] = {};   // [m][kt]
        __builtin_amdgcn_s_setprio(1);
#pragma unroll
        for (int kt = 0; kt < 2; ++kt)
#pragma unroll
            for (int s = 0; s < 4; ++s) {
                bf16x8 kf = *(const bf16x8*)(ks + rb + s * 2048 + kt * 512);
                sA[0][kt] = __builtin_amdgcn_mfma_f32_32x32x16_bf16(kf, qf[0][s], sA[0][kt], 0, 0, 0);
                sA[1][kt] = __builtin_amdgcn_mfma_f32_32x32x16_bf16(kf, qf[1][s], sA[1][kt], 0, 0, 0);
            }
        __builtin_amdgcn_s_setprio(0);

        // ---- mask (uniform LDS word; all-ones -> branch never taken) ----
        const unsigned long long z = mz[t];
        if (z) {
#pragma unroll
            for (int m = 0; m < 2; ++m)
#pragma unroll
                for (int kt = 0; kt < 2; ++kt)
#pragma unroll
                    for (int r = 0; r < 16; ++r) {
                        int k = kt * 32 + (r & 3) + 8 * (r >> 2) + (hi << 2);
                        if ((z >> k) & 1) sA[m][kt][r] = -3e38f;
                    }
        }

        // ---- no-max softmax: p = exp2(s); li += sum ----
        bf16x8 pa[2][2][2];     // [m][kt][sl]
#pragma unroll
        for (int m = 0; m < 2; ++m) {
#pragma unroll
            for (int kt = 0; kt < 2; ++kt)
#pragma unroll
                for (int r = 0; r < 16; ++r)
                    sA[m][kt][r] = exp2a(sA[m][kt][r]);

            f32x16 vs = sA[m][0] + sA[m][1];
            float s0 = vs[0] + vs[1],   s1 = vs[2] + vs[3];
            float s2 = vs[4] + vs[5],   s3 = vs[6] + vs[7];
            float s4 = vs[8] + vs[9],   s5 = vs[10] + vs[11];
            float s6 = vs[12] + vs[13], s7 = vs[14] + vs[15];
            float t0 = s0 + s1, t1 = s2 + s3, t2 = s4 + s5, t3 = s6 + s7;
            float sum = (t0 + t1) + (t2 + t3);
            sum += __shfl_xor(sum, 32, 64);
            li[m] += sum;

            // pack P -> A-frags: native v_cvt_pk_bf16_f32 (V^T pre-permuted)
#pragma unroll
            for (int kt = 0; kt < 2; ++kt) {
                union { unsigned u[4]; bf16x8 v; } f0, f1;
                f0.u[0] = pkbf(sA[m][kt][0],  sA[m][kt][1]);
                f0.u[1] = pkbf(sA[m][kt][2],  sA[m][kt][3]);
                f0.u[2] = pkbf(sA[m][kt][4],  sA[m][kt][5]);
                f0.u[3] = pkbf(sA[m][kt][6],  sA[m][kt][7]);
                f1.u[0] = pkbf(sA[m][kt][8],  sA[m][kt][9]);
                f1.u[1] = pkbf(sA[m][kt][10], sA[m][kt][11]);
                f1.u[2] = pkbf(sA[m][kt][12], sA[m][kt][13]);
                f1.u[3] = pkbf(sA[m][kt][14], sA[m][kt][15]);
                pa[m][kt][0] = f0.v;
                pa[m][kt][1] = f1.v;
            }
        }

        // ---- PV: O[q][d] += P * V; B-frag row=nd*32+l31, chunk=kt*4+sl*2+hi --
        __builtin_amdgcn_s_setprio(1);
#pragma unroll
        for (int kt = 0; kt < 2; ++kt)
#pragma unroll
            for (int sl = 0; sl < 2; ++sl) {
                bf16x8 vb[2];
#pragma unroll
                for (int nd = 0; nd < 2; ++nd)
                    vb[nd] = *(const bf16x8*)(vt + rb + (kt * 4 + sl * 2) * 1024 + nd * 512);
#pragma unroll
                for (int m = 0; m < 2; ++m)
#pragma unroll
                    for (int nd = 0; nd < 2; ++nd)
                        o[m][nd] = __builtin_amdgcn_mfma_f32_32x32x16_bf16(
                            pa[m][kt][sl], vb[nd], o[m][nd], 0, 0, 0);
            }
        __builtin_amdgcn_s_setprio(0);
    };

    stage(0, 0);

    for (int t = 0; t < 31; ++t) {
        stage((t + 1) % 3, (t + 1) * 64);             // tile t+1 in flight
        asm volatile("s_waitcnt vmcnt(4)" ::: "memory");  // tile t landed
        __builtin_amdgcn_s_barrier();
        __builtin_amdgcn_sched_barrier(0);
        body(t % 3, t);
    }
    asm volatile("s_waitcnt vmcnt(0)" ::: "memory");      // last tile landed
    __builtin_amdgcn_s_barrier();
    __builtin_amdgcn_sched_barrier(0);
    body(31 % 3, 31);

    // ---- epilogue: ctx[b][q][h*64+d] ----
#pragma unroll
    for (int m = 0; m < 2; ++m) {
        float rinv = 1.0f / li[m];
#pragma unroll
        for (int r = 0; r < 16; ++r) {
            int cr = (r & 3) + 8 * (r >> 2) + (hi << 2);
            float rv = __shfl(rinv, cr, 32);
            int q = q0 + m * 32 + cr;
#pragma unroll
            for (int nd = 0; nd < 2; ++nd) {
                int d = hh * 64 + nd * 32 + l31;
                ctx[((size_t)bb * 2048 + q) * 1024 + d] = f2bf(o[m][nd][r] * rv);
            }
        }
    }
}

// ---------------- launcher ----------------
extern "C" void kernel_launch(void* const* d_in, const int* in_sizes, int n_in,
                              void* d_out, int out_size, void* d_ws, size_t ws_size,
                              hipStream_t stream)
{
    const float* x    = (const float*)d_in[0];
    const int*   mask = (const int*)d_in[1];
    const float* wq = (const float*)d_in[2];
    const float* bq = (const float*)d_in[3];
    const float* wk = (const float*)d_in[4];
    const float* bk = (const float*)d_in[5];
    const float* wv = (const float*)d_in[6];
    const float* bv = (const float*)d_in[7];
    const float* wo = (const float*)d_in[8];
    const float* bo = (const float*)d_in[9];
    float* out = (float*)d_out;

    char* ws = (char*)d_ws;
    short* Xb  = (short*)(ws + 0);               // 16 MB
    short* Wqb = (short*)(ws + (16ull << 20));   // 2 MB
    short* Wkb = (short*)(ws + (18ull << 20));
    short* Wvb = (short*)(ws + (20ull << 20));
    short* Wob = (short*)(ws + (22ull << 20));
    short* Qb  = (short*)(ws + (24ull << 20));   // 16 MB  [64][2048][64]
    short* Kb  = (short*)(ws + (40ull << 20));   // 16 MB  [64][2048][64]
    short* VT  = (short*)(ws + (56ull << 20));   // 16 MB  [64][64][2048] (k-permuted)
    short* Ctx = (short*)(ws + (72ull << 20));   // 16 MB
    unsigned long long* MW = (unsigned long long*)(ws + (88ull << 20)); // 1 KB

    const int M = 8192, Kd = 1024;

    cvt_kernel<<<(M * Kd / 4 + 255) / 256, 256, 0, stream>>>(
        x, (unsigned*)Xb, M * Kd / 4);
    cvt4_kernel<<<4096, 256, 0, stream>>>(
        wq, wk, wv, wo,
        (unsigned*)Wqb, (unsigned*)Wkb,
        (unsigned*)Wvb, (unsigned*)Wob);
    maskw_kernel<<<32, 256, 0, stream>>>(mask, MW);

    // fused QKV: grid (8 N-blocks, 3 sel x 32 M-blocks), 512 threads
    gemm256<0><<<dim3(8, 96), 512, 0, stream>>>(
        Xb, Wqb, Wkb, Wvb, bq, bk, bv,
        (void*)Qb, (void*)Kb, (void*)VT);

    attn_kernel<<<dim3(8, 64), 256, 0, stream>>>(Qb, Kb, VT, MW,
                                                 (unsigned short*)Ctx);

    // output projection: grid (8, 32), 512 threads
    gemm256<1><<<dim3(8, 32), 512, 0, stream>>>(
        Ctx, Wob, nullptr, nullptr, bo, nullptr, nullptr,
        (void*)out, nullptr, nullptr);
}

// Round 14
// 181.884 us; speedup vs baseline: 1.3730x; 1.3730x over previous
//
#include <hip/hip_runtime.h>
#include <hip/hip_bf16.h>
#include <stdint.h>

typedef __attribute__((ext_vector_type(8))) short bf16x8;
typedef __attribute__((ext_vector_type(4))) float f32x4;
typedef __attribute__((ext_vector_type(16))) float f32x16;

__device__ __forceinline__ unsigned short f2bf(float x) {
    union { float f; unsigned u; } u; u.f = x;
    unsigned r = u.u + 0x7FFFu + ((u.u >> 16) & 1u);
    return (unsigned short)(r >> 16);
}

// native packed f32->bf16 (gfx950 has no builtin; header fn is software RNE)
__device__ __forceinline__ unsigned pkbf(float a, float b) {
    unsigned r;
    asm("v_cvt_pk_bf16_f32 %0, %1, %2" : "=v"(r) : "v"(a), "v"(b));
    return r;
}

__device__ __forceinline__ float exp2a(float x) {
    float r; asm("v_exp_f32 %0, %1" : "=v"(r) : "v"(x)); return r;
}

__device__ __forceinline__ void gload_lds16(const void* g, void* s) {
    __builtin_amdgcn_global_load_lds(
        (const __attribute__((address_space(1))) void*)g,
        (__attribute__((address_space(3))) void*)s,
        16, 0, 0);
}

#define LOG2E 1.44269504088896f

// ---------------- fused prep: X cvt + 4 weight cvts + mask words -----------
// grid 12320 x 256: [0,8192) X (2^21 float4 groups), [8192,12288) weights
// (4 x 2^18 groups), [12288,12320) mask ballot words.
__global__ void prep_kernel(const float* __restrict__ x,
                            const float* __restrict__ w0, const float* __restrict__ w1,
                            const float* __restrict__ w2, const float* __restrict__ w3,
                            const int* __restrict__ mask,
                            unsigned* __restrict__ xo,
                            unsigned* __restrict__ o0, unsigned* __restrict__ o1,
                            unsigned* __restrict__ o2, unsigned* __restrict__ o3,
                            unsigned long long* __restrict__ mw)
{
    int bid = blockIdx.x;
    if (bid < 8192) {
        int i = bid * 256 + threadIdx.x;
        float4 v = ((const float4*)x)[i];
        uint2 o;
        o.x = pkbf(v.x, v.y);
        o.y = pkbf(v.z, v.w);
        ((uint2*)xo)[i] = o;
    } else if (bid < 12288) {
        int j = (bid - 8192) * 256 + threadIdx.x;
        int w = j >> 18, jj = j & 262143;
        const float* src = (w == 0) ? w0 : (w == 1) ? w1 : (w == 2) ? w2 : w3;
        unsigned* dst = (w == 0) ? o0 : (w == 1) ? o1 : (w == 2) ? o2 : o3;
        float4 v = ((const float4*)src)[jj];
        uint2 o;
        o.x = pkbf(v.x, v.y);
        o.y = pkbf(v.z, v.w);
        ((uint2*)dst)[jj] = o;
    } else {
        int gw = (bid - 12288) * 4 + (threadIdx.x >> 6);
        int lane = threadIdx.x & 63;
        int b = gw >> 5, t = gw & 31;
        unsigned long long z = __ballot(mask[b * 2048 + t * 64 + lane] == 0);
        if (lane == 0) mw[gw] = z;
    }
}

// ---------------- fused QKV GEMM: C = X * W^T, bf16 in, fp32 acc ----------
// 1D grid 1536. XCD-grouping swizzle: bid -> xcd=bid&7, s=bid>>3;
// B-tile outer (bxn=s>>3 in [0,24)), A-slice inner (g=s&7); bm=(g*8+xcd)*128.
// Per XCD: 8 A-slices (2MB, L2-resident) x 24 B-tiles (each fetched once).
// sel = bxn>>3 (0:Q scaled log2e/8, 1:K, 2:V^T k-permuted)
__global__ __launch_bounds__(256, 2)
void gemm_qkv(const short* __restrict__ X,
              const short* __restrict__ Wq, const short* __restrict__ Wk,
              const short* __restrict__ Wv,
              const float* __restrict__ bq, const float* __restrict__ bk,
              const float* __restrict__ bv,
              unsigned short* __restrict__ Qo, unsigned short* __restrict__ Ko,
              unsigned short* __restrict__ VTo)
{
    __shared__ short As[128 * 64];
    __shared__ short Bs[128 * 64];

    const int tid  = threadIdx.x;
    const int lane = tid & 63;
    const int wave = tid >> 6;

    const int bid = blockIdx.x;
    const int xcd = bid & 7;
    const int s   = bid >> 3;
    const int bxn = s >> 3;          // [0,24): B-tile (sel,bn)
    const int g   = s & 7;           // [0,8):  A-slice within XCD
    const int sel = bxn >> 3;
    const int bn  = (bxn & 7) * 128;
    const int bm  = (g * 8 + xcd) * 128;
    const int K = 1024;

    const short* B = (sel == 0) ? Wq : (sel == 1) ? Wk : Wv;
    const float* bias = (sel == 0) ? bq : (sel == 1) ? bk : bv;

    const int wm = (wave >> 1) * 64;
    const int wn = (wave & 1) * 64;

    f32x4 acc[4][4] = {};

    int sR[4], sC[4];
#pragma unroll
    for (int p = 0; p < 4; ++p) {
        int L = p * 4096 + tid * 16;
        int r = L >> 7;
        int c = (L & 127) ^ ((r & 7) << 4);
        sR[p] = r; sC[p] = c >> 1;
    }

    for (int k0 = 0; k0 < K; k0 += 64) {
        __syncthreads();
#pragma unroll
        for (int p = 0; p < 4; ++p) {
            gload_lds16(X + (size_t)(bm + sR[p]) * K + k0 + sC[p],
                        (char*)As + p * 4096 + wave * 1024);
            gload_lds16(B + (size_t)(bn + sR[p]) * K + k0 + sC[p],
                        (char*)Bs + p * 4096 + wave * 1024);
        }
        __syncthreads();
#pragma unroll
        for (int ks = 0; ks < 2; ++ks) {
            bf16x8 af[4];
#pragma unroll
            for (int m = 0; m < 4; ++m) {
                int row  = wm + m * 16 + (lane & 15);
                int boff = (ks * 64 + (lane >> 4) * 16) ^ ((row & 7) << 4);
                af[m] = *(const bf16x8*)((const char*)As + row * 128 + boff);
            }
#pragma unroll
            for (int n = 0; n < 4; ++n) {
                int row  = wn + n * 16 + (lane & 15);
                int boff = (ks * 64 + (lane >> 4) * 16) ^ ((row & 7) << 4);
                bf16x8 bfr = *(const bf16x8*)((const char*)Bs + row * 128 + boff);
#pragma unroll
                for (int m = 0; m < 4; ++m)
                    acc[m][n] = __builtin_amdgcn_mfma_f32_16x16x32_bf16(
                        af[m], bfr, acc[m][n], 0, 0, 0);
            }
        }
    }

    const int ccol  = lane & 15;
    const int crow0 = (lane >> 4) * 4;
#pragma unroll
    for (int n = 0; n < 4; ++n) {
        int gn = bn + wn + n * 16 + ccol;
        float bv2 = bias[gn];
        int h = gn >> 6, d = gn & 63;
#pragma unroll
        for (int m = 0; m < 4; ++m) {
            int gm0 = bm + wm + m * 16 + crow0;
            int b = gm0 >> 11, q = gm0 & 2047;
            if (sel == 2) {
                // V^T with k-position perm: swap middle 4-groups in each 16-block
                int g4 = (q >> 2) & 3;
                int qp = q ^ (((g4 + 1) & 2) ? 12 : 0);
                size_t base = ((size_t)(b * 16 + h) * 64 + d) * 2048 + qp;
                uint2 w2;
                w2.x = pkbf(acc[m][n][0] + bv2, acc[m][n][1] + bv2);
                w2.y = pkbf(acc[m][n][2] + bv2, acc[m][n][3] + bv2);
                *(uint2*)(VTo + base) = w2;
            } else {
                unsigned short* out = (sel == 0) ? Qo : Ko;
                float scale = (sel == 0) ? (0.125f * LOG2E) : 1.0f;
                size_t base = ((size_t)(b * 16 + h) * 2048 + q) * 64 + d;
#pragma unroll
                for (int r = 0; r < 4; ++r)
                    out[base + (size_t)r * 64] = f2bf((acc[m][n][r] + bv2) * scale);
            }
        }
    }
}

// ---------------- output projection GEMM: out fp32 = Ctx * Wo^T + bo ------
// 1D grid 512 (FIX r13: was 256, covered only half of M). xcd=bid&7,
// s=bid>>3 in [0,64); bm=((s&7)*8+xcd)*128 (64 M-tiles), bn=(s>>3)*128 (8).
__global__ __launch_bounds__(256, 2)
void gemm_o(const short* __restrict__ A, const short* __restrict__ B,
            const float* __restrict__ bias, float* __restrict__ Out)
{
    __shared__ short As[128 * 64];
    __shared__ short Bs[128 * 64];

    const int tid  = threadIdx.x;
    const int lane = tid & 63;
    const int wave = tid >> 6;

    const int bid = blockIdx.x;
    const int xcd = bid & 7;
    const int s   = bid >> 3;
    const int bm  = ((s & 7) * 8 + xcd) * 128;
    const int bn  = (s >> 3) * 128;

    const int wm = (wave >> 1) * 64;
    const int wn = (wave & 1) * 64;
    const int K = 1024, N = 1024;

    f32x4 acc[4][4] = {};

    int sR[4], sC[4];
#pragma unroll
    for (int p = 0; p < 4; ++p) {
        int L = p * 4096 + tid * 16;
        int r = L >> 7;
        int c = (L & 127) ^ ((r & 7) << 4);
        sR[p] = r; sC[p] = c >> 1;
    }

    for (int k0 = 0; k0 < K; k0 += 64) {
        __syncthreads();
#pragma unroll
        for (int p = 0; p < 4; ++p) {
            gload_lds16(A + (size_t)(bm + sR[p]) * K + k0 + sC[p],
                        (char*)As + p * 4096 + wave * 1024);
            gload_lds16(B + (size_t)(bn + sR[p]) * K + k0 + sC[p],
                        (char*)Bs + p * 4096 + wave * 1024);
        }
        __syncthreads();
#pragma unroll
        for (int ks = 0; ks < 2; ++ks) {
            bf16x8 af[4];
#pragma unroll
            for (int m = 0; m < 4; ++m) {
                int row  = wm + m * 16 + (lane & 15);
                int boff = (ks * 64 + (lane >> 4) * 16) ^ ((row & 7) << 4);
                af[m] = *(const bf16x8*)((const char*)As + row * 128 + boff);
            }
#pragma unroll
            for (int n = 0; n < 4; ++n) {
                int row  = wn + n * 16 + (lane & 15);
                int boff = (ks * 64 + (lane >> 4) * 16) ^ ((row & 7) << 4);
                bf16x8 bfr = *(const bf16x8*)((const char*)Bs + row * 128 + boff);
#pragma unroll
                for (int m = 0; m < 4; ++m)
                    acc[m][n] = __builtin_amdgcn_mfma_f32_16x16x32_bf16(
                        af[m], bfr, acc[m][n], 0, 0, 0);
            }
        }
    }

    const int ccol  = lane & 15;
    const int crow0 = (lane >> 4) * 4;
#pragma unroll
    for (int n = 0; n < 4; ++n) {
        int gn = bn + wn + n * 16 + ccol;
        float bv = bias[gn];
#pragma unroll
        for (int m = 0; m < 4; ++m) {
            int gm0 = bm + wm + m * 16 + crow0;
#pragma unroll
            for (int r = 0; r < 4; ++r)
                Out[(size_t)(gm0 + r) * N + gn] = acc[m][n][r] + bv;
        }
    }
}

// ---------------- flash attention (32x32 mfma, 3-slot ring, counted vmcnt) -
// Q,K: bf16 [64][2048][64] (Q pre-scaled by log2e/8); VT: bf16 [64][64][2048]
// (k-permuted). mw: mask ballot words. ctx out bf16 [4][2048][1024]
// m=2 (64 q-rows/wave), grid (8,64). Chunked conflict-free LDS (r8).
__global__ __launch_bounds__(256, 2)
void attn_kernel(const short* __restrict__ Q, const short* __restrict__ Kg,
                 const short* __restrict__ VTg,
                 const unsigned long long* __restrict__ mw,
                 unsigned short* __restrict__ ctx)
{
    __shared__ __align__(16) short Ks[3][4096];   // 8KB/slot: [c][row] 16B units
    __shared__ __align__(16) short Vt[3][4096];   // 8KB/slot: [c][d-row]
    __shared__ unsigned long long mz[32];

    const int tid  = threadIdx.x;
    const int lane = tid & 63;
    const int wave = tid >> 6;
    const int l31  = lane & 31;
    const int hi   = lane >> 5;

    // XCD swizzle: 8 q-tiles of a (b,h) share one XCD's L2
    const int lin = blockIdx.y * 8 + blockIdx.x;   // gridDim = (8, 64)
    const int bh  = (lin & 7) * 8 + ((lin >> 3) & 7);
    const int qt  = lin >> 6;
    const int bb = bh >> 4, hh = bh & 15;

    const size_t hbase = (size_t)bh * (2048 * 64);
    const short* Qb  = Q   + hbase;
    const short* Kb  = Kg  + hbase;
    const short* VTb = VTg + hbase;      // [64][2048]
    const unsigned long long* mwb = mw + bb * 32;

    const int q0 = qt * 256 + wave * 64;

    // every wave writes all 32 mask words (identical values; self-visible)
    if (lane < 32) mz[lane] = mwb[lane];

    // Q fragments (B-operand): col=q=lane&31, k^=hi*8+e
    bf16x8 qf[2][4];
#pragma unroll
    for (int m = 0; m < 2; ++m)
#pragma unroll
        for (int s = 0; s < 4; ++s) {
            int row = q0 + m * 32 + l31;
            qf[m][s] = *(const bf16x8*)(Qb + (size_t)row * 64 + s * 16 + hi * 8);
        }

    // per-lane LDS byte base
    const int rb = hi * 1024 + l31 * 16;

    f32x16 o[2][2] = {};            // [m][nd]
    float li[2] = { 0.f, 0.f };

    // stage tile kt0/64 into ring slot: LDS[c][row], c=p*4+wave, row=lane
    auto stage = [&](int slot, int kt0) {
#pragma unroll
        for (int p = 0; p < 2; ++p) {
            gload_lds16(Kb + (size_t)(kt0 + lane) * 64 + (p * 4 + wave) * 8,
                        (char*)&Ks[slot][0] + p * 4096 + wave * 1024);
            gload_lds16(VTb + (size_t)lane * 2048 + kt0 + (p * 4 + wave) * 8,
                        (char*)&Vt[slot][0] + p * 4096 + wave * 1024);
        }
    };

    auto body = [&](int slot, int t) {
        const char* ks = (const char*)&Ks[slot][0];
        const char* vt = (const char*)&Vt[slot][0];

        // ---- QK^T (swapped): S^T[k][q]; A-frag row=kt*32+l31, chunk=2s+hi ----
        f32x16 sA[2][2] = {};   // [m][kt]
        __builtin_amdgcn_s_setprio(1);
#pragma unroll
        for (int kt = 0; kt < 2; ++kt)
#pragma unroll
            for (int s = 0; s < 4; ++s) {
                bf16x8 kf = *(const bf16x8*)(ks + rb + s * 2048 + kt * 512);
                sA[0][kt] = __builtin_amdgcn_mfma_f32_32x32x16_bf16(kf, qf[0][s], sA[0][kt], 0, 0, 0);
                sA[1][kt] = __builtin_amdgcn_mfma_f32_32x32x16_bf16(kf, qf[1][s], sA[1][kt], 0, 0, 0);
            }
        __builtin_amdgcn_s_setprio(0);

        // ---- mask (uniform LDS word; all-ones -> branch never taken) ----
        const unsigned long long z = mz[t];
        if (z) {
#pragma unroll
            for (int m = 0; m < 2; ++m)
#pragma unroll
                for (int kt = 0; kt < 2; ++kt)
#pragma unroll
                    for (int r = 0; r < 16; ++r) {
                        int k = kt * 32 + (r & 3) + 8 * (r >> 2) + (hi << 2);
                        if ((z >> k) & 1) sA[m][kt][r] = -3e38f;
                    }
        }

        // ---- no-max softmax: p = exp2(s); li += sum ----
        bf16x8 pa[2][2][2];     // [m][kt][sl]
#pragma unroll
        for (int m = 0; m < 2; ++m) {
#pragma unroll
            for (int kt = 0; kt < 2; ++kt)
#pragma unroll
                for (int r = 0; r < 16; ++r)
                    sA[m][kt][r] = exp2a(sA[m][kt][r]);

            f32x16 vs = sA[m][0] + sA[m][1];
            float s0 = vs[0] + vs[1],   s1 = vs[2] + vs[3];
            float s2 = vs[4] + vs[5],   s3 = vs[6] + vs[7];
            float s4 = vs[8] + vs[9],   s5 = vs[10] + vs[11];
            float s6 = vs[12] + vs[13], s7 = vs[14] + vs[15];
            float t0 = s0 + s1, t1 = s2 + s3, t2 = s4 + s5, t3 = s6 + s7;
            float sum = (t0 + t1) + (t2 + t3);
            sum += __shfl_xor(sum, 32, 64);
            li[m] += sum;

            // pack P -> A-frags: native v_cvt_pk_bf16_f32 (V^T pre-permuted)
#pragma unroll
            for (int kt = 0; kt < 2; ++kt) {
                union { unsigned u[4]; bf16x8 v; } f0, f1;
                f0.u[0] = pkbf(sA[m][kt][0],  sA[m][kt][1]);
                f0.u[1] = pkbf(sA[m][kt][2],  sA[m][kt][3]);
                f0.u[2] = pkbf(sA[m][kt][4],  sA[m][kt][5]);
                f0.u[3] = pkbf(sA[m][kt][6],  sA[m][kt][7]);
                f1.u[0] = pkbf(sA[m][kt][8],  sA[m][kt][9]);
                f1.u[1] = pkbf(sA[m][kt][10], sA[m][kt][11]);
                f1.u[2] = pkbf(sA[m][kt][12], sA[m][kt][13]);
                f1.u[3] = pkbf(sA[m][kt][14], sA[m][kt][15]);
                pa[m][kt][0] = f0.v;
                pa[m][kt][1] = f1.v;
            }
        }

        // ---- PV: O[q][d] += P * V; B-frag row=nd*32+l31, chunk=kt*4+sl*2+hi --
        __builtin_amdgcn_s_setprio(1);
#pragma unroll
        for (int kt = 0; kt < 2; ++kt)
#pragma unroll
            for (int sl = 0; sl < 2; ++sl) {
                bf16x8 vb[2];
#pragma unroll
                for (int nd = 0; nd < 2; ++nd)
                    vb[nd] = *(const bf16x8*)(vt + rb + (kt * 4 + sl * 2) * 1024 + nd * 512);
#pragma unroll
                for (int m = 0; m < 2; ++m)
#pragma unroll
                    for (int nd = 0; nd < 2; ++nd)
                        o[m][nd] = __builtin_amdgcn_mfma_f32_32x32x16_bf16(
                            pa[m][kt][sl], vb[nd], o[m][nd], 0, 0, 0);
            }
        __builtin_amdgcn_s_setprio(0);
    };

    stage(0, 0);

    for (int t = 0; t < 31; ++t) {
        stage((t + 1) % 3, (t + 1) * 64);             // tile t+1 in flight
        asm volatile("s_waitcnt vmcnt(4)" ::: "memory");  // tile t landed
        __builtin_amdgcn_s_barrier();
        __builtin_amdgcn_sched_barrier(0);
        body(t % 3, t);
    }
    asm volatile("s_waitcnt vmcnt(0)" ::: "memory");      // last tile landed
    __builtin_amdgcn_s_barrier();
    __builtin_amdgcn_sched_barrier(0);
    body(31 % 3, 31);

    // ---- epilogue: ctx[b][q][h*64+d] ----
#pragma unroll
    for (int m = 0; m < 2; ++m) {
        float rinv = 1.0f / li[m];
#pragma unroll
        for (int r = 0; r < 16; ++r) {
            int cr = (r & 3) + 8 * (r >> 2) + (hi << 2);
            float rv = __shfl(rinv, cr, 32);
            int q = q0 + m * 32 + cr;
#pragma unroll
            for (int nd = 0; nd < 2; ++nd) {
                int d = hh * 64 + nd * 32 + l31;
                ctx[((size_t)bb * 2048 + q) * 1024 + d] = f2bf(o[m][nd][r] * rv);
            }
        }
    }
}

// ---------------- launcher ----------------
extern "C" void kernel_launch(void* const* d_in, const int* in_sizes, int n_in,
                              void* d_out, int out_size, void* d_ws, size_t ws_size,
                              hipStream_t stream)
{
    const float* x    = (const float*)d_in[0];
    const int*   mask = (const int*)d_in[1];
    const float* wq = (const float*)d_in[2];
    const float* bq = (const float*)d_in[3];
    const float* wk = (const float*)d_in[4];
    const float* bk = (const float*)d_in[5];
    const float* wv = (const float*)d_in[6];
    const float* bv = (const float*)d_in[7];
    const float* wo = (const float*)d_in[8];
    const float* bo = (const float*)d_in[9];
    float* out = (float*)d_out;

    char* ws = (char*)d_ws;
    short* Xb  = (short*)(ws + 0);               // 16 MB
    short* Wqb = (short*)(ws + (16ull << 20));   // 2 MB
    short* Wkb = (short*)(ws + (18ull << 20));
    short* Wvb = (short*)(ws + (20ull << 20));
    short* Wob = (short*)(ws + (22ull << 20));
    short* Qb  = (short*)(ws + (24ull << 20));   // 16 MB  [64][2048][64]
    short* Kb  = (short*)(ws + (40ull << 20));   // 16 MB  [64][2048][64]
    short* VT  = (short*)(ws + (56ull << 20));   // 16 MB  [64][64][2048] (k-permuted)
    short* Ctx = (short*)(ws + (72ull << 20));   // 16 MB
    unsigned long long* MW = (unsigned long long*)(ws + (88ull << 20)); // 1 KB

    prep_kernel<<<12320, 256, 0, stream>>>(
        x, wq, wk, wv, wo, mask,
        (unsigned*)Xb, (unsigned*)Wqb, (unsigned*)Wkb,
        (unsigned*)Wvb, (unsigned*)Wob, MW);

    gemm_qkv<<<1536, 256, 0, stream>>>(
        Xb, Wqb, Wkb, Wvb, bq, bk, bv,
        (unsigned short*)Qb, (unsigned short*)Kb, (unsigned short*)VT);

    attn_kernel<<<dim3(8, 64), 256, 0, stream>>>(Qb, Kb, VT, MW,
                                                 (unsigned short*)Ctx);

    gemm_o<<<512, 256, 0, stream>>>(Ctx, Wob, bo, out);
}